// Round 1
// baseline (293.566 us; speedup 1.0000x reference)
//
#include <hip/hip_runtime.h>
#include <cstdint>
#include <cstddef>

// ---------------- problem constants ----------------
#define TOKENS   65536      // B*N = 16*4096
#define KDIM     256        // model dim
#define HIDDEN   1024       // 4*dim
#define BM       128        // tokens per block
#define HC       64         // hidden chunk width
#define NCHUNK   16         // HIDDEN / HC
#define NTHREADS 512        // 8 waves
#define NBLOCKS  (TOKENS / BM)

using f16x8 = __attribute__((ext_vector_type(8))) _Float16;
using f16x4 = __attribute__((ext_vector_type(4))) _Float16;
using f32x4 = __attribute__((ext_vector_type(4))) float;

// fp16 hi/lo split weights, stored pre-transposed + pre-swizzled per 64-wide
// hidden chunk so that a LINEAR global_load_lds stage produces the swizzled
// LDS image directly (guide rule 21: swizzle both sides via the source).
__device__ __align__(16) _Float16 g_W1h[NCHUNK * HC * KDIM];   // [c][n][k] images
__device__ __align__(16) _Float16 g_W1l[NCHUNK * HC * KDIM];
__device__ __align__(16) _Float16 g_W2h[NCHUNK * KDIM * HC];   // [c][n][k] images
__device__ __align__(16) _Float16 g_W2l[NCHUNK * KDIM * HC];
__device__ __align__(16) _Float16 g_Whh[16 * KDIM];            // head: rows j(16) x k(256)
__device__ __align__(16) _Float16 g_Whl[16 * KDIM];

// ---------------- prep: split + transpose + swizzle weights ----------------
__global__ __launch_bounds__(256) void prep_kernel(
    const float* __restrict__ W1, const float* __restrict__ W2,
    const float* __restrict__ Wval, const float* __restrict__ Wvec) {
  const int tid = blockIdx.x * 256 + threadIdx.x;
  if (tid < 32768) {
    // W1 granules: chunk c, n in [0,64), granule g in [0,32) of 8 k-elems
    const int c = tid >> 11, rem = tid & 2047;
    const int n = rem & 63, g = rem >> 6;            // lanes -> consecutive n (coalesced reads)
    const uint32_t p = ((uint32_t)((n * 512 + g * 16) ^ ((n & 7) << 4))) >> 1;
    const int base = c * 16384;
    const int hid = c * 64 + n;
#pragma unroll
    for (int j = 0; j < 8; ++j) {
      const float wv = W1[(g * 8 + j) * HIDDEN + hid];   // W1[k][hid]
      const _Float16 hi = (_Float16)wv;
      g_W1h[base + p + j] = hi;
      g_W1l[base + p + j] = (_Float16)(wv - (float)hi);
    }
  } else if (tid < 65536) {
    // W2 granules: chunk c, n in [0,256), granule g in [0,8)
    const int t = tid - 32768;
    const int c = t >> 11, rem = t & 2047;
    const int n = rem & 255, g = rem >> 8;
    const uint32_t p = ((uint32_t)((n * 128 + g * 16) ^ ((n & 7) << 4))) >> 1;
    const int base = c * 16384;
#pragma unroll
    for (int j = 0; j < 8; ++j) {
      const float wv = W2[(c * 64 + g * 8 + j) * KDIM + n];   // W2[hid][n]
      const _Float16 hi = (_Float16)wv;
      g_W2h[base + p + j] = hi;
      g_W2l[base + p + j] = (_Float16)(wv - (float)hi);
    }
  } else if (tid < 65536 + 4096) {
    // head weights: row j16 (0..15: 0-2 Wval cols, 3-11 Wvec cols, 12-15 zero)
    const int e = tid - 65536;
    const int j16 = e >> 8, k = e & 255;
    float wv = 0.f;
    if (j16 < 3) wv = Wval[k * 3 + j16];
    else if (j16 < 12) wv = Wvec[k * 9 + (j16 - 3)];
    const _Float16 hi = (_Float16)wv;
    g_Whh[e] = hi;
    g_Whl[e] = (_Float16)(wv - (float)hi);
  }
}

// stage one 32KB region: 8 waves x 4KB each, 4x 1KB global_load_lds_dwordx4
__device__ __forceinline__ void stage_wave_32k(const char* gsrc, char* ldst,
                                               int w, int lane) {
#pragma unroll
  for (int i = 0; i < 4; ++i) {
    const int o = w * 4096 + i * 1024;
    __builtin_amdgcn_global_load_lds(
        (__attribute__((address_space(1))) void*)(void*)(gsrc + o + lane * 16),
        (__attribute__((address_space(3))) void*)(ldst + o), 16, 0, 0);
  }
}

// ---------------- fused FFN + heads + QR/cov ----------------
// LDS map (128KB dynamic):
//   chunk loop:  w1h @0  w1l @32K  w2h @64K  w2l @96K ; G overlay: gh @0, gl @16K
//   P0 x-stage:  xs_hi @0..64K  xs_lo @64K..128K
//   epilogue:    hbuf (fp16 h) @0..64K ; hstg (f32 [128][16]) @64K
__global__ __launch_bounds__(NTHREADS, 2) void fused_kernel(
    const float* __restrict__ x, const float* __restrict__ b1,
    const float* __restrict__ b2, const float* __restrict__ bval,
    const float* __restrict__ bvec, float* __restrict__ out) {
  extern __shared__ char smem[];
  const int tid  = threadIdx.x;
  const int lane = tid & 63;
  const int w    = tid >> 6;     // wave 0..7
  const int wm   = w >> 1;       // row group (32 rows)
  const int wn   = w & 1;        // col group
  const int l15  = lane & 15;
  const int lg   = lane >> 4;
  const int64_t R = (int64_t)blockIdx.x * BM;

  // ---- P0: stage x tile as fp16 hi/lo (row-swizzled) ----
  {
    const float* xg = x + R * KDIM;
#pragma unroll
    for (int i = 0; i < 16; ++i) {
      const int fidx = tid + NTHREADS * i;      // 8192 float4s total
      const int row  = fidx >> 6;
      const int f4   = fidx & 63;
      const float4 v = *(const float4*)(xg + row * KDIM + f4 * 4);
      const _Float16 h0 = (_Float16)v.x, h1 = (_Float16)v.y,
                     h2 = (_Float16)v.z, h3 = (_Float16)v.w;
      f16x4 hv = {h0, h1, h2, h3};
      f16x4 lv = {(_Float16)(v.x - (float)h0), (_Float16)(v.y - (float)h1),
                  (_Float16)(v.z - (float)h2), (_Float16)(v.w - (float)h3)};
      const uint32_t off = (uint32_t)(row * 512) +
                           (((uint32_t)(f4 * 8)) ^ ((row & 7) << 4));
      *(f16x4*)(smem + off)         = hv;
      *(f16x4*)(smem + 65536 + off) = lv;
    }
  }
  __syncthreads();

  // ---- P1: persistent x A-fragments (rows wm*32..+31, all K) ----
  f16x8 xah[2][8], xal[2][8];
#pragma unroll
  for (int mt = 0; mt < 2; ++mt) {
    const int row = wm * 32 + mt * 16 + l15;
    const uint32_t rbase = row * 512;
    const uint32_t swz = (row & 7) << 4;
#pragma unroll
    for (int ks = 0; ks < 8; ++ks) {
      const uint32_t off = rbase + (((uint32_t)((ks * 32 + lg * 8) * 2)) ^ swz);
      xah[mt][ks] = *(const f16x8*)(smem + off);
      xal[mt][ks] = *(const f16x8*)(smem + 65536 + off);
    }
  }
  __syncthreads();

  const f32x4 z4 = {0.f, 0.f, 0.f, 0.f};
  f32x4 acc2[2][8];
#pragma unroll
  for (int mt = 0; mt < 2; ++mt)
#pragma unroll
    for (int nt = 0; nt < 8; ++nt) acc2[mt][nt] = z4;

  // ---- chunk loop over hidden dim ----
#pragma unroll 1
  for (int hc = 0; hc < NCHUNK; ++hc) {
    {
      const size_t cb = (size_t)hc * 32768;
      stage_wave_32k((const char*)g_W1h + cb, smem,         w, lane);
      stage_wave_32k((const char*)g_W1l + cb, smem + 32768, w, lane);
      stage_wave_32k((const char*)g_W2h + cb, smem + 65536, w, lane);
      stage_wave_32k((const char*)g_W2l + cb, smem + 98304, w, lane);
    }
    __syncthreads();   // stages drained (vmcnt(0) at barrier)

    // GEMM1: accG = xh*W1h + xh*W1l + xl*W1h   (f32 MFMA accum)
    f32x4 accG[2][2] = {{z4, z4}, {z4, z4}};
#pragma unroll
    for (int ks = 0; ks < 8; ++ks) {
      f16x8 bh[2], bl[2];
#pragma unroll
      for (int nt = 0; nt < 2; ++nt) {
        const int n = wn * 32 + nt * 16 + l15;
        const uint32_t off = (uint32_t)(n * 512) +
                             (((uint32_t)((ks * 32 + lg * 8) * 2)) ^ ((n & 7) << 4));
        bh[nt] = *(const f16x8*)(smem + off);
        bl[nt] = *(const f16x8*)(smem + 32768 + off);
      }
#pragma unroll
      for (int mt = 0; mt < 2; ++mt)
#pragma unroll
        for (int nt = 0; nt < 2; ++nt) {
          accG[mt][nt] = __builtin_amdgcn_mfma_f32_16x16x32_f16(xah[mt][ks], bh[nt], accG[mt][nt], 0, 0, 0);
          accG[mt][nt] = __builtin_amdgcn_mfma_f32_16x16x32_f16(xah[mt][ks], bl[nt], accG[mt][nt], 0, 0, 0);
          accG[mt][nt] = __builtin_amdgcn_mfma_f32_16x16x32_f16(xal[mt][ks], bh[nt], accG[mt][nt], 0, 0, 0);
        }
    }
    __syncthreads();   // W1 buffers dead -> G overlay safe

    // bias + gelu(tanh approx, matching jax default) + fp16 split + write G
#pragma unroll
    for (int nt = 0; nt < 2; ++nt) {
      const float bv = b1[hc * HC + wn * 32 + nt * 16 + l15];
#pragma unroll
      for (int mt = 0; mt < 2; ++mt) {
#pragma unroll
        for (int r = 0; r < 4; ++r) {
          const float v  = accG[mt][nt][r] + bv;
          const float u  = 0.79788456080286535588f * (v + 0.044715f * v * v * v);
          const float e  = __expf(2.f * u);
          const float th = 1.f - 2.f / (e + 1.f);     // tanh(u), inf-safe
          const float gv = 0.5f * v * (1.f + th);
          const _Float16 gh = (_Float16)gv;
          const _Float16 gl = (_Float16)(gv - (float)gh);
          const int grow = wm * 32 + mt * 16 + lg * 4 + r;
          const int gcol = wn * 32 + nt * 16 + l15;
          const uint32_t off = (uint32_t)(grow * 128) +
                               (((uint32_t)(gcol * 2)) ^ ((grow & 7) << 4));
          *(_Float16*)(smem + off)         = gh;
          *(_Float16*)(smem + 16384 + off) = gl;
        }
      }
    }
    __syncthreads();   // G visible to all waves

    // GEMM2: acc2 += gh*W2h + gh*W2l + gl*W2h
#pragma unroll
    for (int ks2 = 0; ks2 < 2; ++ks2) {
      const uint32_t k2 = (uint32_t)((ks2 * 32 + lg * 8) * 2);
      f16x8 ah[2], al[2];
#pragma unroll
      for (int mt = 0; mt < 2; ++mt) {
        const int row = wm * 32 + mt * 16 + l15;
        const uint32_t off = (uint32_t)(row * 128) + (k2 ^ ((row & 7) << 4));
        ah[mt] = *(const f16x8*)(smem + off);
        al[mt] = *(const f16x8*)(smem + 16384 + off);
      }
#pragma unroll
      for (int nt = 0; nt < 8; ++nt) {
        const int n = wn * 128 + nt * 16 + l15;
        const uint32_t off = (uint32_t)(n * 128) + (k2 ^ ((n & 7) << 4));
        const f16x8 bh = *(const f16x8*)(smem + 65536 + off);
        const f16x8 bl = *(const f16x8*)(smem + 98304 + off);
#pragma unroll
        for (int mt = 0; mt < 2; ++mt) {
          acc2[mt][nt] = __builtin_amdgcn_mfma_f32_16x16x32_f16(ah[mt], bh, acc2[mt][nt], 0, 0, 0);
          acc2[mt][nt] = __builtin_amdgcn_mfma_f32_16x16x32_f16(ah[mt], bl, acc2[mt][nt], 0, 0, 0);
          acc2[mt][nt] = __builtin_amdgcn_mfma_f32_16x16x32_f16(al[mt], bh, acc2[mt][nt], 0, 0, 0);
        }
      }
    }
    __syncthreads();   // G + W2 dead -> next chunk may restage
  }

  // ---- epilogue: h = x + FFN + b2 (exact f32 residual), write h_hi ----
  {
    const float* xg = x + R * KDIM;
#pragma unroll
    for (int nt = 0; nt < 8; ++nt) {
      const float bv = b2[wn * 128 + nt * 16 + l15];
#pragma unroll
      for (int mt = 0; mt < 2; ++mt) {
#pragma unroll
        for (int r = 0; r < 4; ++r) {
          const int row = wm * 32 + mt * 16 + lg * 4 + r;
          const int col = wn * 128 + nt * 16 + l15;
          const float h = acc2[mt][nt][r] + xg[row * KDIM + col] + bv;
          acc2[mt][nt][r] = h;
          const uint32_t off = (uint32_t)(row * 512) +
                               (((uint32_t)(col * 2)) ^ ((row & 7) << 4));
          *(_Float16*)(smem + off) = (_Float16)h;
        }
      }
    }
  }
  __syncthreads();

  // ---- head GEMM pass 1+2: hh*Whh + hh*Whl (16 cols: 3 val, 9 vec, 4 pad) ----
  f32x4 hacc = z4;
  const int hrow = wm * 32 + wn * 16 + l15;    // each wave owns 16 token rows
  const uint32_t hbase = hrow * 512;
  const uint32_t hswz  = (hrow & 7) << 4;
#pragma unroll
  for (int ks = 0; ks < 8; ++ks) {
    const uint32_t off = hbase + (((uint32_t)((ks * 32 + lg * 8) * 2)) ^ hswz);
    const f16x8 af  = *(const f16x8*)(smem + off);
    const f16x8 bhf = *(const f16x8*)(g_Whh + l15 * 256 + ks * 32 + lg * 8);
    const f16x8 blf = *(const f16x8*)(g_Whl + l15 * 256 + ks * 32 + lg * 8);
    hacc = __builtin_amdgcn_mfma_f32_16x16x32_f16(af, bhf, hacc, 0, 0, 0);
    hacc = __builtin_amdgcn_mfma_f32_16x16x32_f16(af, blf, hacc, 0, 0, 0);
  }
  __syncthreads();   // all waves done reading h_hi

  // ---- write h_lo over the same buffer ----
#pragma unroll
  for (int nt = 0; nt < 8; ++nt) {
#pragma unroll
    for (int mt = 0; mt < 2; ++mt) {
#pragma unroll
      for (int r = 0; r < 4; ++r) {
        const int row = wm * 32 + mt * 16 + lg * 4 + r;
        const int col = wn * 128 + nt * 16 + l15;
        const float h = acc2[mt][nt][r];
        const _Float16 hh = (_Float16)h;
        const uint32_t off = (uint32_t)(row * 512) +
                             (((uint32_t)(col * 2)) ^ ((row & 7) << 4));
        *(_Float16*)(smem + off) = (_Float16)(h - (float)hh);
      }
    }
  }
  __syncthreads();

  // ---- head pass 3: hl*Whh ----
#pragma unroll
  for (int ks = 0; ks < 8; ++ks) {
    const uint32_t off = hbase + (((uint32_t)((ks * 32 + lg * 8) * 2)) ^ hswz);
    const f16x8 af  = *(const f16x8*)(smem + off);
    const f16x8 bhf = *(const f16x8*)(g_Whh + l15 * 256 + ks * 32 + lg * 8);
    hacc = __builtin_amdgcn_mfma_f32_16x16x32_f16(af, bhf, hacc, 0, 0, 0);
  }
  const float hb = (l15 < 3) ? bval[l15] : ((l15 < 12) ? bvec[l15 - 3] : 0.f);
#pragma unroll
  for (int r = 0; r < 4; ++r) hacc[r] += hb;

  // ---- gather 12 head values per token (intra-wave via LDS), QR + cov ----
  float* hstg = (float*)(smem + 65536);   // [128][16] f32, disjoint from hbuf
#pragma unroll
  for (int r = 0; r < 4; ++r) {
    const int row = wm * 32 + wn * 16 + lg * 4 + r;
    hstg[row * 16 + l15] = hacc[r];
  }
  // producer/consumer are the same wave; compiler inserts the lgkm wait
  if (lane < 16) {
    const int row = wm * 32 + wn * 16 + lane;
    const float* hs = hstg + row * 16;
    float sp[3];
#pragma unroll
    for (int i = 0; i < 3; ++i) {
      const float s = hs[i];
      sp[i] = fmaxf(s, 0.f) + log1pf(__expf(-fabsf(s)));   // softplus
    }
    // V[r][c] = hs[3 + 3r + c]; QR columns; cov invariant to column signs
    const float a0 = hs[3], a1 = hs[6], a2 = hs[9];
    const float b0 = hs[4], bc1 = hs[7], bc2 = hs[10];
    const float na = a0 * a0 + a1 * a1 + a2 * a2;
    const float ia = 1.f / sqrtf(fmaxf(na, 1e-30f));
    const float q00 = a0 * ia, q01 = a1 * ia, q02 = a2 * ia;
    const float d  = q00 * b0 + q01 * bc1 + q02 * bc2;
    const float u0 = b0 - d * q00, u1 = bc1 - d * q01, u2 = bc2 - d * q02;
    const float nu = u0 * u0 + u1 * u1 + u2 * u2;
    const float iu = 1.f / sqrtf(fmaxf(nu, 1e-30f));
    const float q10 = u0 * iu, q11 = u1 * iu, q12 = u2 * iu;
    const float q20 = q01 * q12 - q02 * q11;
    const float q21 = q02 * q10 - q00 * q12;
    const float q22 = q00 * q11 - q01 * q10;
    const float c00 = sp[0]*q00*q00 + sp[1]*q10*q10 + sp[2]*q20*q20 + 1e-8f;
    const float c11 = sp[0]*q01*q01 + sp[1]*q11*q11 + sp[2]*q21*q21 + 1e-8f;
    const float c22 = sp[0]*q02*q02 + sp[1]*q12*q12 + sp[2]*q22*q22 + 1e-8f;
    const float c01 = sp[0]*q00*q01 + sp[1]*q10*q11 + sp[2]*q20*q21;
    const float c02 = sp[0]*q00*q02 + sp[1]*q10*q12 + sp[2]*q20*q22;
    const float c12 = sp[0]*q01*q02 + sp[1]*q11*q12 + sp[2]*q21*q22;
    float* o = out + (size_t)(R + row) * 9;
    o[0] = c00; o[1] = c01; o[2] = c02;
    o[3] = c01; o[4] = c11; o[5] = c12;
    o[6] = c02; o[7] = c12; o[8] = c22;
  }
}

extern "C" void kernel_launch(void* const* d_in, const int* in_sizes, int n_in,
                              void* d_out, int out_size, void* d_ws, size_t ws_size,
                              hipStream_t stream) {
  const float* x    = (const float*)d_in[0];
  const float* W1   = (const float*)d_in[1];
  const float* b1   = (const float*)d_in[2];
  const float* W2   = (const float*)d_in[3];
  const float* b2   = (const float*)d_in[4];
  const float* Wval = (const float*)d_in[5];
  const float* bval = (const float*)d_in[6];
  const float* Wvec = (const float*)d_in[7];
  const float* bvec = (const float*)d_in[8];
  float* out = (float*)d_out;
  (void)in_sizes; (void)n_in; (void)out_size; (void)d_ws; (void)ws_size;

  // allow 128KB dynamic LDS (idempotent, capture-safe: not a stream op)
  hipFuncSetAttribute((const void*)fused_kernel,
                      hipFuncAttributeMaxDynamicSharedMemorySize, 131072);

  prep_kernel<<<272, 256, 0, stream>>>(W1, W2, Wval, Wvec);
  fused_kernel<<<NBLOCKS, NTHREADS, 131072, stream>>>(x, b1, b2, bval, bvec, out);
}

// Round 2
// 287.579 us; speedup vs baseline: 1.0208x; 1.0208x over previous
//
#include <hip/hip_runtime.h>
#include <cstdint>
#include <cstddef>

// ---------------- problem constants ----------------
#define TOKENS   65536      // B*N = 16*4096
#define KDIM     256        // model dim
#define HIDDEN   1024       // 4*dim
#define BM       128        // tokens per block
#define HC       32         // hidden chunk width
#define NCHUNK   32         // HIDDEN / HC
#define NTHREADS 512        // 8 waves
#define NBLOCKS  (TOKENS / BM)

// LDS map (148 KB dynamic):
//   buf0 @0      : W1h 16K | W1l 16K | W2h 16K | W2l 16K   (64 KB)
//   buf1 @65536  : same                                     (64 KB)
//   G    @131072 : u32-packed (gh|gl<<16) [128][32]         (16 KB)
//   b1   @147456 : f32[1024]                                ( 4 KB)
//   P0 overlay   : x_hi @0..64K, x_lo @64K..128K (pre-loop only)
//   epilogue     : h fp16 @0..64K, hstg f32[128][16] @65536
#define GOFF  131072
#define B1OFF 147456
#define LDS_BYTES 151552

using f16x8 = __attribute__((ext_vector_type(8))) _Float16;
using f16x4 = __attribute__((ext_vector_type(4))) _Float16;
using f32x4 = __attribute__((ext_vector_type(4))) float;
using u32x4 = __attribute__((ext_vector_type(4))) uint32_t;

// fp16 hi/lo split weights, pre-transposed + pre-swizzled per chunk so a
// LINEAR global_load_lds stage produces the swizzled LDS image directly.
// W1 plane: [c][n=32][k=256], byte = n*512 + ((g*16) ^ ((n&7)<<4))
// W2 plane: [c][n=256][k=32], byte = n*64  + ((g*16) ^ (((n>>1)&3)<<4))
__device__ __align__(16) _Float16 g_W1h[NCHUNK * HC * KDIM];
__device__ __align__(16) _Float16 g_W1l[NCHUNK * HC * KDIM];
__device__ __align__(16) _Float16 g_W2h[NCHUNK * KDIM * HC];
__device__ __align__(16) _Float16 g_W2l[NCHUNK * KDIM * HC];
__device__ __align__(16) _Float16 g_Whh[16 * KDIM];            // head rows j(16) x k(256)
__device__ __align__(16) _Float16 g_Whl[16 * KDIM];

// ---------------- prep: split + transpose + swizzle (dest-coalesced) ----------------
__global__ __launch_bounds__(256) void prep_kernel(
    const float* __restrict__ W1, const float* __restrict__ W2,
    const float* __restrict__ Wval, const float* __restrict__ Wvec) {
  const int tid = blockIdx.x * 256 + threadIdx.x;
  if (tid < 32768) {
    // W1: c(32) x n(32) x gd(32 dest k-octets)
    const int c = tid >> 10, n = (tid >> 5) & 31, gd = tid & 31;
    const int g = gd ^ (n & 7);          // swizzle is involutive on octet index
    const int hid = c * 32 + n;
    f16x8 hv, lv;
#pragma unroll
    for (int j = 0; j < 8; ++j) {
      const float wv = W1[(g * 8 + j) * HIDDEN + hid];
      const _Float16 hi = (_Float16)wv;
      hv[j] = hi;
      lv[j] = (_Float16)(wv - (float)hi);
    }
    const int dst = c * 8192 + n * 256 + gd * 8;
    *(f16x8*)(g_W1h + dst) = hv;
    *(f16x8*)(g_W1l + dst) = lv;
  } else if (tid < 65536) {
    // W2: c(32) x n(256) x gd(4)
    const int t = tid - 32768;
    const int c = t >> 10, n = (t >> 2) & 255, gd = t & 3;
    const int g = gd ^ ((n >> 1) & 3);
    f16x8 hv, lv;
#pragma unroll
    for (int j = 0; j < 8; ++j) {
      const float wv = W2[(c * 32 + g * 8 + j) * KDIM + n];
      const _Float16 hi = (_Float16)wv;
      hv[j] = hi;
      lv[j] = (_Float16)(wv - (float)hi);
    }
    const int dst = c * 8192 + n * 32 + gd * 8;
    *(f16x8*)(g_W2h + dst) = hv;
    *(f16x8*)(g_W2l + dst) = lv;
  } else if (tid < 65536 + 4096) {
    const int e = tid - 65536;
    const int j16 = e >> 8, k = e & 255;
    float wv = 0.f;
    if (j16 < 3) wv = Wval[k * 3 + j16];
    else if (j16 < 12) wv = Wvec[k * 9 + (j16 - 3)];
    const _Float16 hi = (_Float16)wv;
    g_Whh[e] = hi;
    g_Whl[e] = (_Float16)(wv - (float)hi);
  }
}

// issue one chunk's 64KB stage: 8 waves x 8KB, 8x 1KB global_load_lds_dwordx4.
// Exactly 8 VMEM ops per wave -> vmcnt ledger stays exact.
__device__ __forceinline__ void stage_chunk(char* buf, int c, int w, int lane) {
  const int plane = w >> 1, half = w & 1;
  const _Float16* g;
  if      (plane == 0) g = g_W1h;
  else if (plane == 1) g = g_W1l;
  else if (plane == 2) g = g_W2h;
  else                 g = g_W2l;
  const char* s = (const char*)g + (size_t)c * 16384 + half * 8192 + lane * 16;
  char* d = buf + plane * 16384 + half * 8192;   // wave-uniform LDS base
#pragma unroll
  for (int i = 0; i < 8; ++i) {
    __builtin_amdgcn_global_load_lds(
        (__attribute__((address_space(1))) void*)(void*)(s + i * 1024),
        (__attribute__((address_space(3))) void*)(d + i * 1024), 16, 0, 0);
  }
}

__device__ __forceinline__ f16x8 unpack_half(const u32x4 a, const u32x4 b, uint32_t sel) {
  u32x4 r;
  r[0] = __builtin_amdgcn_perm(a[1], a[0], sel);
  r[1] = __builtin_amdgcn_perm(a[3], a[2], sel);
  r[2] = __builtin_amdgcn_perm(b[1], b[0], sel);
  r[3] = __builtin_amdgcn_perm(b[3], b[2], sel);
  return __builtin_bit_cast(f16x8, r);
}

// ---------------- fused FFN + heads + QR/cov ----------------
__global__ __launch_bounds__(NTHREADS, 2) void fused_kernel(
    const float* __restrict__ x, const float* __restrict__ b1,
    const float* __restrict__ b2, const float* __restrict__ bval,
    const float* __restrict__ bvec, float* __restrict__ out) {
  extern __shared__ char smem[];
  const int tid  = threadIdx.x;
  const int lane = tid & 63;
  const int w    = tid >> 6;     // wave 0..7
  const int wm   = w >> 1;       // row group (32 rows)
  const int wn   = w & 1;        // col group
  const int l15  = lane & 15;
  const int lg   = lane >> 4;
  const int64_t R = (int64_t)blockIdx.x * BM;

  // ---- b1 -> LDS table (keeps the K-loop free of stray VMEM ops) ----
  {
    float* b1l = (float*)(smem + B1OFF);
    b1l[tid]       = b1[tid];
    b1l[tid + 512] = b1[tid + 512];
  }

  // ---- P0: stage x tile as fp16 hi/lo (row-swizzled) ----
  {
    const float* xg = x + R * KDIM;
#pragma unroll
    for (int i = 0; i < 16; ++i) {
      const int fidx = tid + NTHREADS * i;      // 8192 float4s total
      const int row  = fidx >> 6;
      const int f4   = fidx & 63;
      const float4 v = *(const float4*)(xg + row * KDIM + f4 * 4);
      const _Float16 h0 = (_Float16)v.x, h1 = (_Float16)v.y,
                     h2 = (_Float16)v.z, h3 = (_Float16)v.w;
      f16x4 hv = {h0, h1, h2, h3};
      f16x4 lv = {(_Float16)(v.x - (float)h0), (_Float16)(v.y - (float)h1),
                  (_Float16)(v.z - (float)h2), (_Float16)(v.w - (float)h3)};
      const uint32_t off = (uint32_t)(row * 512) +
                           (((uint32_t)(f4 * 8)) ^ ((row & 7) << 4));
      *(f16x4*)(smem + off)         = hv;
      *(f16x4*)(smem + 65536 + off) = lv;
    }
  }
  __syncthreads();   // full drain OK here (prefetch not started)

  // ---- P1: persistent x A-fragments (rows wm*32..+31, all K) ----
  f16x8 xah[2][8], xal[2][8];
#pragma unroll
  for (int mt = 0; mt < 2; ++mt) {
    const int row = wm * 32 + mt * 16 + l15;
    const uint32_t rbase = row * 512;
    const uint32_t swz = (row & 7) << 4;
#pragma unroll
    for (int ks = 0; ks < 8; ++ks) {
      const uint32_t off = rbase + (((uint32_t)((ks * 32 + lg * 8) * 2)) ^ swz);
      xah[mt][ks] = *(const f16x8*)(smem + off);
      xal[mt][ks] = *(const f16x8*)(smem + 65536 + off);
    }
  }
  asm volatile("s_waitcnt lgkmcnt(0)" ::: "memory");  // frag reads complete
  __builtin_amdgcn_s_barrier();                       // before weights overwrite x
  __builtin_amdgcn_sched_barrier(0);

  // ---- prologue prefetch: chunks 0 and 1 ----
  stage_chunk(smem,         0, w, lane);
  stage_chunk(smem + 65536, 1, w, lane);

  const f32x4 z4 = {0.f, 0.f, 0.f, 0.f};
  f32x4 acc2[2][8];
#pragma unroll
  for (int mt = 0; mt < 2; ++mt)
#pragma unroll
    for (int nt = 0; nt < 8; ++nt) acc2[mt][nt] = z4;

  // ---- chunk loop: counted-vmcnt double-buffer pipeline ----
#pragma unroll 1
  for (int t = 0; t < NCHUNK; ++t) {
    char* buf = smem + ((t & 1) ? 65536 : 0);
    // wait current chunk landed; keep next chunk's 8 loads in flight
    if (t == NCHUNK - 1) { asm volatile("s_waitcnt vmcnt(0)" ::: "memory"); }
    else                 { asm volatile("s_waitcnt vmcnt(8)" ::: "memory"); }
    __builtin_amdgcn_s_barrier();
    __builtin_amdgcn_sched_barrier(0);

    // GEMM1: pass-split accumulators (6 independent MFMA chains)
    f32x4 accA[2] = {z4, z4}, accB[2] = {z4, z4}, accC[2] = {z4, z4};
    {
      const int n = wn * 16 + l15;
      const uint32_t nbase = (uint32_t)(n * 512);
      const uint32_t nswz  = (uint32_t)((n & 7) << 4);
#pragma unroll
      for (int ks = 0; ks < 8; ++ks) {
        const uint32_t off = nbase + (((uint32_t)(ks * 64 + lg * 16)) ^ nswz);
        const f16x8 bh = *(const f16x8*)(buf + off);
        const f16x8 bl = *(const f16x8*)(buf + 16384 + off);
#pragma unroll
        for (int mt = 0; mt < 2; ++mt) {
          accA[mt] = __builtin_amdgcn_mfma_f32_16x16x32_f16(xah[mt][ks], bh, accA[mt], 0, 0, 0);
          accB[mt] = __builtin_amdgcn_mfma_f32_16x16x32_f16(xah[mt][ks], bl, accB[mt], 0, 0, 0);
          accC[mt] = __builtin_amdgcn_mfma_f32_16x16x32_f16(xal[mt][ks], bh, accC[mt], 0, 0, 0);
        }
      }
    }

    // bias + gelu + fp16 split + u32-packed G write (conflict-light)
    {
      const float bv = ((const float*)(smem + B1OFF))[t * 32 + wn * 16 + l15];
      const int gcol = wn * 16 + l15;
#pragma unroll
      for (int mt = 0; mt < 2; ++mt) {
#pragma unroll
        for (int r = 0; r < 4; ++r) {
          const float v  = accA[mt][r] + accB[mt][r] + accC[mt][r] + bv;
          const float u  = 0.79788456080286535588f * (v + 0.044715f * v * v * v);
          const float e  = __expf(2.f * u);
          const float th = 1.f - 2.f / (e + 1.f);     // tanh(u), inf-safe
          const float gv = 0.5f * v * (1.f + th);
          const _Float16 gh = (_Float16)gv;
          const _Float16 gl = (_Float16)(gv - (float)gh);
          const uint32_t pk = (uint32_t)__builtin_bit_cast(unsigned short, gh) |
                              ((uint32_t)__builtin_bit_cast(unsigned short, gl) << 16);
          const int grow = wm * 32 + mt * 16 + lg * 4 + r;
          const uint32_t off = (uint32_t)(GOFF + grow * 128) +
                               (((uint32_t)(gcol * 4)) ^ ((grow & 7) << 4));
          *(uint32_t*)(smem + off) = pk;
        }
      }
    }
    asm volatile("s_waitcnt lgkmcnt(0)" ::: "memory");  // my G writes committed
    __builtin_amdgcn_s_barrier();                       // G visible to all waves
    __builtin_amdgcn_sched_barrier(0);

    // GEMM2: acc2 += gh*W2h + gh*W2l + gl*W2h
    {
      f16x8 ah[2], al[2];
#pragma unroll
      for (int mt = 0; mt < 2; ++mt) {
        const int row = wm * 32 + mt * 16 + l15;
        const uint32_t sw = (uint32_t)((row & 7) << 4);
        const uint32_t base = (uint32_t)(GOFF + row * 128);
        const u32x4 w0 = *(const u32x4*)(smem + base + (((uint32_t)(lg * 32)) ^ sw));
        const u32x4 w1 = *(const u32x4*)(smem + base + (((uint32_t)(lg * 32 + 16)) ^ sw));
        ah[mt] = unpack_half(w0, w1, 0x05040100u);   // gh lanes
        al[mt] = unpack_half(w0, w1, 0x07060302u);   // gl lanes
      }
#pragma unroll
      for (int nt = 0; nt < 8; ++nt) {
        const int n = wn * 128 + nt * 16 + l15;
        const uint32_t off = (uint32_t)(n * 64) +
                             (((uint32_t)(lg * 16)) ^ (((n >> 1) & 3) << 4));
        const f16x8 bh = *(const f16x8*)(buf + 32768 + off);
        const f16x8 bl = *(const f16x8*)(buf + 49152 + off);
#pragma unroll
        for (int mt = 0; mt < 2; ++mt) {
          acc2[mt][nt] = __builtin_amdgcn_mfma_f32_16x16x32_f16(ah[mt], bh, acc2[mt][nt], 0, 0, 0);
          acc2[mt][nt] = __builtin_amdgcn_mfma_f32_16x16x32_f16(ah[mt], bl, acc2[mt][nt], 0, 0, 0);
          acc2[mt][nt] = __builtin_amdgcn_mfma_f32_16x16x32_f16(al[mt], bh, acc2[mt][nt], 0, 0, 0);
        }
      }
    }
    __builtin_amdgcn_sched_barrier(0);
    __builtin_amdgcn_s_barrier();       // all waves done with buf[cur] + G
    __builtin_amdgcn_sched_barrier(0);
    if (t + 2 < NCHUNK) stage_chunk(buf, t + 2, w, lane);   // prefetch into freed buffer
  }

  // ---- epilogue: h = x + FFN + b2 (exact f32 residual), write h_hi ----
  {
    const float* xg = x + R * KDIM;
#pragma unroll
    for (int nt = 0; nt < 8; ++nt) {
      const float bv = b2[wn * 128 + nt * 16 + l15];
#pragma unroll
      for (int mt = 0; mt < 2; ++mt) {
#pragma unroll
        for (int r = 0; r < 4; ++r) {
          const int row = wm * 32 + mt * 16 + lg * 4 + r;
          const int col = wn * 128 + nt * 16 + l15;
          const float h = acc2[mt][nt][r] + xg[row * KDIM + col] + bv;
          acc2[mt][nt][r] = h;
          const uint32_t off = (uint32_t)(row * 512) +
                               (((uint32_t)(col * 2)) ^ ((row & 7) << 4));
          *(_Float16*)(smem + off) = (_Float16)h;
        }
      }
    }
  }
  __syncthreads();

  // ---- head GEMM pass 1+2: hh*Whh + hh*Whl ----
  f32x4 hacc = z4;
  const int hrow = wm * 32 + wn * 16 + l15;    // each wave owns 16 token rows
  const uint32_t hbase = hrow * 512;
  const uint32_t hswz  = (hrow & 7) << 4;
#pragma unroll
  for (int ks = 0; ks < 8; ++ks) {
    const uint32_t off = hbase + (((uint32_t)((ks * 32 + lg * 8) * 2)) ^ hswz);
    const f16x8 af  = *(const f16x8*)(smem + off);
    const f16x8 bhf = *(const f16x8*)(g_Whh + l15 * 256 + ks * 32 + lg * 8);
    const f16x8 blf = *(const f16x8*)(g_Whl + l15 * 256 + ks * 32 + lg * 8);
    hacc = __builtin_amdgcn_mfma_f32_16x16x32_f16(af, bhf, hacc, 0, 0, 0);
    hacc = __builtin_amdgcn_mfma_f32_16x16x32_f16(af, blf, hacc, 0, 0, 0);
  }
  __syncthreads();

  // ---- write h_lo over the same buffer ----
#pragma unroll
  for (int nt = 0; nt < 8; ++nt) {
#pragma unroll
    for (int mt = 0; mt < 2; ++mt) {
#pragma unroll
      for (int r = 0; r < 4; ++r) {
        const int row = wm * 32 + mt * 16 + lg * 4 + r;
        const int col = wn * 128 + nt * 16 + l15;
        const float h = acc2[mt][nt][r];
        const _Float16 hh = (_Float16)h;
        const uint32_t off = (uint32_t)(row * 512) +
                             (((uint32_t)(col * 2)) ^ ((row & 7) << 4));
        *(_Float16*)(smem + off) = (_Float16)(h - (float)hh);
      }
    }
  }
  __syncthreads();

  // ---- head pass 3: hl*Whh ----
#pragma unroll
  for (int ks = 0; ks < 8; ++ks) {
    const uint32_t off = hbase + (((uint32_t)((ks * 32 + lg * 8) * 2)) ^ hswz);
    const f16x8 af  = *(const f16x8*)(smem + off);
    const f16x8 bhf = *(const f16x8*)(g_Whh + l15 * 256 + ks * 32 + lg * 8);
    hacc = __builtin_amdgcn_mfma_f32_16x16x32_f16(af, bhf, hacc, 0, 0, 0);
  }
  const float hb = (l15 < 3) ? bval[l15] : ((l15 < 12) ? bvec[l15 - 3] : 0.f);
#pragma unroll
  for (int r = 0; r < 4; ++r) hacc[r] += hb;

  // ---- gather 12 head values per token, QR + cov ----
  float* hstg = (float*)(smem + 65536);   // disjoint from h buffer
#pragma unroll
  for (int r = 0; r < 4; ++r) {
    const int row = wm * 32 + wn * 16 + lg * 4 + r;
    hstg[row * 16 + l15] = hacc[r];
  }
  if (lane < 16) {
    const int row = wm * 32 + wn * 16 + lane;
    const float* hs = hstg + row * 16;
    float sp[3];
#pragma unroll
    for (int i = 0; i < 3; ++i) {
      const float s = hs[i];
      sp[i] = fmaxf(s, 0.f) + log1pf(__expf(-fabsf(s)));   // softplus
    }
    const float a0 = hs[3], a1 = hs[6], a2 = hs[9];
    const float b0 = hs[4], bc1 = hs[7], bc2 = hs[10];
    const float na = a0 * a0 + a1 * a1 + a2 * a2;
    const float ia = 1.f / sqrtf(fmaxf(na, 1e-30f));
    const float q00 = a0 * ia, q01 = a1 * ia, q02 = a2 * ia;
    const float d  = q00 * b0 + q01 * bc1 + q02 * bc2;
    const float u0 = b0 - d * q00, u1 = bc1 - d * q01, u2 = bc2 - d * q02;
    const float nu = u0 * u0 + u1 * u1 + u2 * u2;
    const float iu = 1.f / sqrtf(fmaxf(nu, 1e-30f));
    const float q10 = u0 * iu, q11 = u1 * iu, q12 = u2 * iu;
    const float q20 = q01 * q12 - q02 * q11;
    const float q21 = q02 * q10 - q00 * q12;
    const float q22 = q00 * q11 - q01 * q10;
    const float c00 = sp[0]*q00*q00 + sp[1]*q10*q10 + sp[2]*q20*q20 + 1e-8f;
    const float c11 = sp[0]*q01*q01 + sp[1]*q11*q11 + sp[2]*q21*q21 + 1e-8f;
    const float c22 = sp[0]*q02*q02 + sp[1]*q12*q12 + sp[2]*q22*q22 + 1e-8f;
    const float c01 = sp[0]*q00*q01 + sp[1]*q10*q11 + sp[2]*q20*q21;
    const float c02 = sp[0]*q00*q02 + sp[1]*q10*q12 + sp[2]*q20*q22;
    const float c12 = sp[0]*q01*q02 + sp[1]*q11*q12 + sp[2]*q21*q22;
    float* o = out + (size_t)(R + row) * 9;
    o[0] = c00; o[1] = c01; o[2] = c02;
    o[3] = c01; o[4] = c11; o[5] = c12;
    o[6] = c02; o[7] = c12; o[8] = c22;
  }
}

extern "C" void kernel_launch(void* const* d_in, const int* in_sizes, int n_in,
                              void* d_out, int out_size, void* d_ws, size_t ws_size,
                              hipStream_t stream) {
  const float* x    = (const float*)d_in[0];
  const float* W1   = (const float*)d_in[1];
  const float* b1   = (const float*)d_in[2];
  const float* W2   = (const float*)d_in[3];
  const float* b2   = (const float*)d_in[4];
  const float* Wval = (const float*)d_in[5];
  const float* bval = (const float*)d_in[6];
  const float* Wvec = (const float*)d_in[7];
  const float* bvec = (const float*)d_in[8];
  float* out = (float*)d_out;
  (void)in_sizes; (void)n_in; (void)out_size; (void)d_ws; (void)ws_size;

  hipFuncSetAttribute((const void*)fused_kernel,
                      hipFuncAttributeMaxDynamicSharedMemorySize, LDS_BYTES);

  prep_kernel<<<272, 256, 0, stream>>>(W1, W2, Wval, Wvec);
  fused_kernel<<<NBLOCKS, NTHREADS, LDS_BYTES, stream>>>(x, b1, b2, bval, bvec, out);
}